// Round 2
// baseline (1481.507 us; speedup 1.0000x reference)
//
#include <hip/hip_runtime.h>
#include <hip/hip_bf16.h>
#include <stdint.h>

typedef __bf16 bf16x8 __attribute__((ext_vector_type(8)));
typedef float f32x4 __attribute__((ext_vector_type(4)));
typedef unsigned short ushort_t;

static constexpr int kB = 16;
static constexpr int kN = 3137;           // 1 + 56*56
static constexpr long kM = (long)kB * kN; // 50192
static constexpr int kDinner = 2048;

__device__ __forceinline__ float bf2f(ushort_t u) {
  return __uint_as_float(((unsigned)u) << 16);
}
__device__ __forceinline__ ushort_t f2bf(float f) {
  __hip_bfloat16 h = __float2bfloat16(f);
  return *reinterpret_cast<ushort_t*>(&h);
}
// async global->LDS, 16B/lane; lds dest wave-uniform base + lane*16
__device__ __forceinline__ void gload16(const void* g, void* l) {
  __builtin_amdgcn_global_load_lds(
      (const __attribute__((address_space(1))) unsigned int*)g,
      (__attribute__((address_space(3))) unsigned int*)(uintptr_t)l,
      16, 0, 0);
}

// ---------------- prep kernels ----------------

__global__ __launch_bounds__(256) void cast_kernel(const float* __restrict__ s,
                                                   ushort_t* __restrict__ d, long n4) {
  long i = (long)blockIdx.x * 256 + threadIdx.x;
  if (i >= n4) return;
  float4 v = *(const float4*)(s + i * 4);
  ushort4 o;
  o.x = f2bf(v.x); o.y = f2bf(v.y); o.z = f2bf(v.z); o.w = f2bf(v.w);
  *(ushort4*)(d + i * 4) = o;
}

// dst[d][e] = bf16(src[e][d]), n x n
__global__ __launch_bounds__(256) void transpose_cast_kernel(const float* __restrict__ src,
                                                             ushort_t* __restrict__ dst,
                                                             int n) {
  __shared__ float tile[32][33];
  const int tx = blockIdx.x * 32, ty = blockIdx.y * 32;
  const int x = threadIdx.x & 31, y0 = threadIdx.x >> 5;  // y0 in 0..7
#pragma unroll
  for (int j = 0; j < 32; j += 8)
    tile[y0 + j][x] = src[(long)(ty + y0 + j) * n + tx + x];
  __syncthreads();
#pragma unroll
  for (int j = 0; j < 32; j += 8)
    dst[(long)(tx + y0 + j) * n + ty + x] = f2bf(tile[x][y0 + j]);
}

// c[o] = bf[o] + sum_e wf[o][e]*bp[e]
__global__ __launch_bounds__(256) void cvec_kernel(const float* __restrict__ wf,
                                                   const float* __restrict__ bp,
                                                   const float* __restrict__ bfv,
                                                   float* __restrict__ c) {
  int o = blockIdx.x;
  __shared__ float red[4];
  float s = 0.f;
  for (int e = threadIdx.x; e < 2048; e += 256) s += wf[(long)o * 2048 + e] * bp[e];
#pragma unroll
  for (int off = 32; off >= 1; off >>= 1) s += __shfl_xor(s, off);
  if ((threadIdx.x & 63) == 0) red[threadIdx.x >> 6] = s;
  __syncthreads();
  if (threadIdx.x == 0) c[o] = bfv[o] + red[0] + red[1] + red[2] + red[3];
}

// LayerNorm over 256 dims; 4 rows/block; fp32 in, bf16 out
__global__ __launch_bounds__(256) void ln_kernel(const float* __restrict__ x,
                                                 const float* __restrict__ gw,
                                                 const float* __restrict__ gb,
                                                 ushort_t* __restrict__ out, long M) {
  long row = (long)blockIdx.x * 4 + (threadIdx.x >> 6);
  if (row >= M) return;
  int lane = threadIdx.x & 63;
  float4 v = *(const float4*)(x + row * 256 + lane * 4);
  float s = v.x + v.y + v.z + v.w;
  float s2 = v.x * v.x + v.y * v.y + v.z * v.z + v.w * v.w;
#pragma unroll
  for (int o = 32; o >= 1; o >>= 1) {
    s += __shfl_xor(s, o);
    s2 += __shfl_xor(s2, o);
  }
  float mu = s * (1.f / 256.f);
  float var = fmaxf(s2 * (1.f / 256.f) - mu * mu, 0.f);
  float rs = rsqrtf(var + 1e-5f);
  ushort4 o4;
  o4.x = f2bf((v.x - mu) * rs * gw[lane * 4 + 0] + gb[lane * 4 + 0]);
  o4.y = f2bf((v.y - mu) * rs * gw[lane * 4 + 1] + gb[lane * 4 + 1]);
  o4.z = f2bf((v.z - mu) * rs * gw[lane * 4 + 2] + gb[lane * 4 + 2]);
  o4.w = f2bf((v.w - mu) * rs * gw[lane * 4 + 3] + gb[lane * 4 + 3]);
  *(ushort4*)(out + row * 256 + lane * 4) = o4;
}

// row l2-normalize width-2048 bf16 matrix in place.
// QMODE: also A[row0+row] = (row . wg)/16.  else: also scale by G[b][d] (G chunk-based).
template <bool QMODE>
__global__ __launch_bounds__(256) void rownorm_kernel(ushort_t* __restrict__ mat,
                                                      const float* __restrict__ wg,
                                                      float* __restrict__ Av, long row0,
                                                      const float* __restrict__ G) {
  long lrow = blockIdx.x;
  int t = threadIdx.x;
  __shared__ float red[8];
  uint4 raw = *(const uint4*)(mat + lrow * 2048 + t * 8);
  ushort_t* u = (ushort_t*)&raw;
  float v[8];
  float ss = 0.f;
#pragma unroll
  for (int j = 0; j < 8; ++j) {
    v[j] = bf2f(u[j]);
    ss += v[j] * v[j];
  }
#pragma unroll
  for (int o = 32; o >= 1; o >>= 1) ss += __shfl_xor(ss, o);
  int w = t >> 6;
  if ((t & 63) == 0) red[w] = ss;
  __syncthreads();
  float rs = 1.f / fmaxf(sqrtf(red[0] + red[1] + red[2] + red[3]), 1e-12f);
  if constexpr (QMODE) {
    float av = 0.f;
#pragma unroll
    for (int j = 0; j < 8; ++j) {
      float qn = v[j] * rs;
      u[j] = f2bf(qn);
      av += qn * wg[t * 8 + j];
    }
    *(uint4*)(mat + lrow * 2048 + t * 8) = raw;
#pragma unroll
    for (int o = 32; o >= 1; o >>= 1) av += __shfl_xor(av, o);
    if ((t & 63) == 0) red[4 + w] = av;
    __syncthreads();
    if (t == 0) Av[row0 + lrow] = (red[4] + red[5] + red[6] + red[7]) * 0.0625f;
  } else {
    int b = (int)(lrow / kN);  // chunk-local batch
    const float* g = G + (long)b * 2048 + t * 8;
#pragma unroll
    for (int j = 0; j < 8; ++j) u[j] = f2bf(v[j] * rs * g[j]);
    *(uint4*)(mat + lrow * 2048 + t * 8) = raw;
  }
}

// invA[b0+blk] = 1/max(||A_b||, eps)
__global__ __launch_bounds__(256) void anorm_kernel(const float* __restrict__ Av,
                                                    float* __restrict__ invA, int b0) {
  int b = b0 + blockIdx.x;
  __shared__ float red[4];
  float s = 0.f;
  for (int n = threadIdx.x; n < kN; n += 256) {
    float a = Av[(long)b * kN + n];
    s += a * a;
  }
#pragma unroll
  for (int o = 32; o >= 1; o >>= 1) s += __shfl_xor(s, o);
  if ((threadIdx.x & 63) == 0) red[threadIdx.x >> 6] = s;
  __syncthreads();
  if (threadIdx.x == 0)
    invA[b] = 1.f / fmaxf(sqrtf(red[0] + red[1] + red[2] + red[3]), 1e-12f);
}

// G[b][d] = invA[b] * sum_n Av[b*kN+n] * qc[by*kN+n][d]
__global__ __launch_bounds__(256) void g_kernel(const float* __restrict__ Av,
                                                const float* __restrict__ invA,
                                                const ushort_t* __restrict__ qc,
                                                float* __restrict__ G, int b0) {
  int by = blockIdx.y;
  int b = b0 + by;
  int d = blockIdx.x * 256 + threadIdx.x;
  const ushort_t* p = qc + (long)by * kN * 2048 + d;
  const float* ap = Av + (long)b * kN;
  float acc = 0.f;
#pragma unroll 8
  for (int n = 0; n < kN; ++n) acc += ap[n] * bf2f(p[(long)n * 2048]);
  G[(long)b * 2048 + d] = acc * invA[b];
}

// ---------------- GEMM: C = A @ W^T (+epilogue).  A: MxK bf16, W: NoutxK bf16 ----
// 128x128 tile, 4 waves (2x2 of 64x64), BK=32, mfma_f32_16x16x32_bf16.
// EPI 5: bf16 store (+bias if non-null)
// EPI 2: f32 store: v + auxf[idx]   (bias = cvec)
// EPI 6: f32 RMW:   out0[idx] += v
// EPI 3: bf16 gelu(v)
// EPI 4: f32 RMW:   out0[idx] += (row%kN==0 ? bf2f(auxb[idx]) : v)
template <int EPI, int LDO>
__global__ __launch_bounds__(256) void gemm_kernel(
    const ushort_t* __restrict__ A, const ushort_t* __restrict__ W, int M, int K,
    const float* __restrict__ bias, const float* __restrict__ auxf,
    const ushort_t* __restrict__ auxb, void* __restrict__ out0) {
  __shared__ ushort_t As[128 * 32];
  __shared__ ushort_t Ws[128 * 32];
  const int t = threadIdx.x;
  const int wave = t >> 6;
  const int lane = t & 63;
  const int n0 = blockIdx.x * 128;
  const int m0 = blockIdx.y * 128;
  const int wm = (wave >> 1) * 64;
  const int wn = (wave & 1) * 64;

  f32x4 acc[4][4];
#pragma unroll
  for (int i = 0; i < 4; ++i)
#pragma unroll
    for (int j = 0; j < 4; ++j) acc[i][j] = f32x4{0.f, 0.f, 0.f, 0.f};

  const int r4 = t >> 2;
  const int c8 = (t & 3) * 8;
  long ar0 = m0 + r4;      if (ar0 > M - 1) ar0 = M - 1;
  long ar1 = m0 + 64 + r4; if (ar1 > M - 1) ar1 = M - 1;
  const ushort_t* gA0 = A + ar0 * K + c8;
  const ushort_t* gA1 = A + ar1 * K + c8;
  const ushort_t* gW0 = W + (long)(n0 + r4) * K + c8;
  const ushort_t* gW1 = W + (long)(n0 + 64 + r4) * K + c8;
  char* la = (char*)As + wave * 1024;
  char* lw = (char*)Ws + wave * 1024;

  const int frow = lane & 15;
  const int kg = lane >> 4;

  for (int k0 = 0; k0 < K; k0 += 32) {
    gload16(gA0 + k0, la);
    gload16(gA1 + k0, la + 4096);
    gload16(gW0 + k0, lw);
    gload16(gW1 + k0, lw + 4096);
    __syncthreads();
    bf16x8 af[4], bw[4];
#pragma unroll
    for (int i = 0; i < 4; ++i)
      af[i] = *(const bf16x8*)&As[(wm + i * 16 + frow) * 32 + kg * 8];
#pragma unroll
    for (int i = 0; i < 4; ++i)
      bw[i] = *(const bf16x8*)&Ws[(wn + i * 16 + frow) * 32 + kg * 8];
#pragma unroll
    for (int mi = 0; mi < 4; ++mi)
#pragma unroll
      for (int ni = 0; ni < 4; ++ni)
        acc[mi][ni] =
            __builtin_amdgcn_mfma_f32_16x16x32_bf16(af[mi], bw[ni], acc[mi][ni], 0, 0, 0);
    __syncthreads();
  }

#pragma unroll
  for (int mi = 0; mi < 4; ++mi) {
#pragma unroll
    for (int ni = 0; ni < 4; ++ni) {
      const int gn = n0 + wn + ni * 16 + frow;
#pragma unroll
      for (int j = 0; j < 4; ++j) {
        const int gmi = m0 + wm + mi * 16 + kg * 4 + j;
        if (gmi >= M) continue;
        const long idx = (long)gmi * LDO + gn;
        float v = acc[mi][ni][j];
        if (bias) v += bias[gn];
        if constexpr (EPI == 5) {
          ((ushort_t*)out0)[idx] = f2bf(v);
        } else if constexpr (EPI == 2) {
          ((float*)out0)[idx] = v + auxf[idx];
        } else if constexpr (EPI == 6) {
          ((float*)out0)[idx] += v;
        } else if constexpr (EPI == 3) {
          ((ushort_t*)out0)[idx] = f2bf(0.5f * v * (1.0f + erff(v * 0.70710678118654752f)));
        } else {  // EPI == 4
          const bool cls = (gmi % kN) == 0;
          const float add = cls ? bf2f(auxb[idx]) : v;
          ((float*)out0)[idx] += add;
        }
      }
    }
  }
}

// ---------------- host ----------------

extern "C" void kernel_launch(void* const* d_in, const int* in_sizes, int n_in,
                              void* d_out, int out_size, void* d_ws, size_t ws_size,
                              hipStream_t stream) {
  const float* x = (const float*)d_in[0];
  const float* n1w = (const float*)d_in[1];
  const float* n1b = (const float*)d_in[2];
  const float* wq = (const float*)d_in[3];
  const float* bq = (const float*)d_in[4];
  const float* wk = (const float*)d_in[5];
  const float* bk = (const float*)d_in[6];
  const float* wg = (const float*)d_in[7];
  const float* wp = (const float*)d_in[8];
  const float* bp = (const float*)d_in[9];
  const float* wf = (const float*)d_in[10];
  const float* bfv = (const float*)d_in[11];
  const float* n2w = (const float*)d_in[12];
  const float* n2b = (const float*)d_in[13];
  const float* w1 = (const float*)d_in[14];
  const float* b1 = (const float*)d_in[15];
  const float* w2 = (const float*)d_in[16];
  const float* b2 = (const float*)d_in[17];
  float* out = (float*)d_out;  // also serves as the fp32 x2 accumulator

  // ---- workspace layout (adaptive chunking over batches) ----
  char* ws = (char*)d_ws;
  size_t off = 0;
  auto alloc = [&](size_t bytes) {
    size_t o = off;
    off += (bytes + 255) & ~(size_t)255;
    return o;
  };
  ushort_t* wq_bf = (ushort_t*)(ws + alloc((size_t)2048 * 256 * 2));
  ushort_t* wk_bf = (ushort_t*)(ws + alloc((size_t)2048 * 256 * 2));
  ushort_t* wpT_bf = (ushort_t*)(ws + alloc((size_t)2048 * 2048 * 2));
  ushort_t* wf_bf = (ushort_t*)(ws + alloc((size_t)256 * 2048 * 2));
  ushort_t* w1_bf = (ushort_t*)(ws + alloc((size_t)1024 * 256 * 2));
  ushort_t* w2_bf = (ushort_t*)(ws + alloc((size_t)256 * 1024 * 2));
  ushort_t* wfp_bf = (ushort_t*)(ws + alloc((size_t)256 * 2048 * 2));
  float* cvec = (float*)(ws + alloc(256 * 4));
  float* Av = (float*)(ws + alloc((size_t)kM * 4));
  float* invA = (float*)(ws + alloc(64));
  float* G = (float*)(ws + alloc((size_t)16 * 2048 * 4));
  ushort_t* xn = (ushort_t*)(ws + alloc((size_t)kM * 256 * 2));
  size_t fixed = off;

  int CH = 0;
  for (int c : {1, 2, 4, 8, 16}) {
    size_t big = (size_t)(16 / c) * kN * 2048 * 2;
    if (fixed + big + 256 <= ws_size) { CH = c; break; }
  }
  if (CH == 0) return;  // cannot fit even minimal footprint
  const int NB = 16 / CH;
  ushort_t* big = (ushort_t*)(ws + alloc((size_t)NB * kN * 2048 * 2));

  auto mt = [](long m) { return (int)((m + 127) / 128); };

  // ---- weight prep ----
  cast_kernel<<<512, 256, 0, stream>>>(wq, wq_bf, 2048 * 256 / 4);
  cast_kernel<<<512, 256, 0, stream>>>(wk, wk_bf, 2048 * 256 / 4);
  cast_kernel<<<512, 256, 0, stream>>>(wf, wf_bf, 256 * 2048 / 4);
  cast_kernel<<<256, 256, 0, stream>>>(w1, w1_bf, 1024 * 256 / 4);
  cast_kernel<<<256, 256, 0, stream>>>(w2, w2_bf, 256 * 1024 / 4);
  transpose_cast_kernel<<<dim3(64, 64), 256, 0, stream>>>(wp, wpT_bf, 2048);
  cvec_kernel<<<256, 256, 0, stream>>>(wf, bp, bfv, cvec);
  // wfp = wf @ wp  (256 x 2048, bf16)
  gemm_kernel<5, 2048><<<dim3(16, 2), 256, 0, stream>>>(
      wf_bf, wpT_bf, 256, 2048, nullptr, nullptr, nullptr, wfp_bf);

  // ---- LN1 (full M) ----
  ln_kernel<<<(int)((kM + 3) / 4), 256, 0, stream>>>(x, n1w, n1b, xn, kM);

  // ---- attention path, chunked over whole batches ----
  for (int c = 0; c < CH; ++c) {
    const int b0 = c * NB;
    const long r0 = (long)b0 * kN;
    const long Mc = (long)NB * kN;
    const int mtc = mt(Mc);
    // q = xn@wq^T + bq
    gemm_kernel<5, 2048><<<dim3(16, mtc), 256, 0, stream>>>(
        xn + r0 * 256, wq_bf, (int)Mc, 256, bq, nullptr, nullptr, big);
    // normalize q rows, A
    rownorm_kernel<true><<<(int)Mc, 256, 0, stream>>>(big, wg, Av, r0, nullptr);
    // ||A|| per batch, G
    anorm_kernel<<<NB, 256, 0, stream>>>(Av, invA, b0);
    g_kernel<<<dim3(8, NB), 256, 0, stream>>>(Av, invA, big, G, b0);
    // out = x + q@wf^T + c
    gemm_kernel<2, 256><<<dim3(2, mtc), 256, 0, stream>>>(
        big, wf_bf, (int)Mc, 2048, cvec, x + r0 * 256, nullptr, out + r0 * 256);
    // k = xn@wk^T + bk
    gemm_kernel<5, 2048><<<dim3(16, mtc), 256, 0, stream>>>(
        xn + r0 * 256, wk_bf, (int)Mc, 256, bk, nullptr, nullptr, big);
    // normalize k rows and scale by G
    rownorm_kernel<false><<<(int)Mc, 256, 0, stream>>>(big, nullptr, nullptr, 0,
                                                       G + (long)b0 * 2048);
    // out += kk@wfp^T
    gemm_kernel<6, 256><<<dim3(2, mtc), 256, 0, stream>>>(
        big, wfp_bf, (int)Mc, 2048, nullptr, nullptr, nullptr, out + r0 * 256);
  }

  // ---- LN2 (full M): out(f32) -> xn ----
  ln_kernel<<<(int)((kM + 3) / 4), 256, 0, stream>>>(out, n2w, n2b, xn, kM);

  // ---- MLP, chunked ----
  for (int c = 0; c < CH; ++c) {
    const long r0 = (long)(c * NB) * kN;
    const long Mc = (long)NB * kN;
    const int mtc = mt(Mc);
    // hdn = gelu(xn2@w1^T + b1)
    gemm_kernel<3, 1024><<<dim3(8, mtc), 256, 0, stream>>>(
        xn + r0 * 256, w1_bf, (int)Mc, 256, b1, nullptr, nullptr, big);
    // out += (cls ? xn2 : hdn@w2^T + b2)
    gemm_kernel<4, 256><<<dim3(2, mtc), 256, 0, stream>>>(
        big, w2_bf, (int)Mc, 1024, b2, nullptr, xn + r0 * 256, out + r0 * 256);
  }
}

// Round 3
// 1282.373 us; speedup vs baseline: 1.1553x; 1.1553x over previous
//
#include <hip/hip_runtime.h>
#include <hip/hip_bf16.h>
#include <stdint.h>

typedef __bf16 bf16x8 __attribute__((ext_vector_type(8)));
typedef float f32x4 __attribute__((ext_vector_type(4)));
typedef unsigned short ushort_t;

static constexpr int kB = 16;
static constexpr int kN = 3137;           // 1 + 56*56
static constexpr long kM = (long)kB * kN; // 50192
static constexpr int kDinner = 2048;
static constexpr int kGS = 128;           // n-split factor for G reduction

__device__ __forceinline__ float bf2f(ushort_t u) {
  return __uint_as_float(((unsigned)u) << 16);
}
__device__ __forceinline__ ushort_t f2bf(float f) {
  __hip_bfloat16 h = __float2bfloat16(f);
  return *reinterpret_cast<ushort_t*>(&h);
}
// async global->LDS, 16B/lane; lds dest wave-uniform base + lane*16
__device__ __forceinline__ void gload16(const void* g, void* l) {
  __builtin_amdgcn_global_load_lds(
      (const __attribute__((address_space(1))) unsigned int*)g,
      (__attribute__((address_space(3))) unsigned int*)(uintptr_t)l,
      16, 0, 0);
}

// ---------------- prep kernels ----------------

__global__ __launch_bounds__(256) void cast_kernel(const float* __restrict__ s,
                                                   ushort_t* __restrict__ d, long n4) {
  long i = (long)blockIdx.x * 256 + threadIdx.x;
  if (i >= n4) return;
  float4 v = *(const float4*)(s + i * 4);
  ushort4 o;
  o.x = f2bf(v.x); o.y = f2bf(v.y); o.z = f2bf(v.z); o.w = f2bf(v.w);
  *(ushort4*)(d + i * 4) = o;
}

// dst[d][e] = bf16(src[e][d]), n x n
__global__ __launch_bounds__(256) void transpose_cast_kernel(const float* __restrict__ src,
                                                             ushort_t* __restrict__ dst,
                                                             int n) {
  __shared__ float tile[32][33];
  const int tx = blockIdx.x * 32, ty = blockIdx.y * 32;
  const int x = threadIdx.x & 31, y0 = threadIdx.x >> 5;  // y0 in 0..7
#pragma unroll
  for (int j = 0; j < 32; j += 8)
    tile[y0 + j][x] = src[(long)(ty + y0 + j) * n + tx + x];
  __syncthreads();
#pragma unroll
  for (int j = 0; j < 32; j += 8)
    dst[(long)(tx + y0 + j) * n + ty + x] = f2bf(tile[x][y0 + j]);
}

// c[o] = bf[o] + sum_e wf[o][e]*bp[e]
__global__ __launch_bounds__(256) void cvec_kernel(const float* __restrict__ wf,
                                                   const float* __restrict__ bp,
                                                   const float* __restrict__ bfv,
                                                   float* __restrict__ c) {
  int o = blockIdx.x;
  __shared__ float red[4];
  float s = 0.f;
  for (int e = threadIdx.x; e < 2048; e += 256) s += wf[(long)o * 2048 + e] * bp[e];
#pragma unroll
  for (int off = 32; off >= 1; off >>= 1) s += __shfl_xor(s, off);
  if ((threadIdx.x & 63) == 0) red[threadIdx.x >> 6] = s;
  __syncthreads();
  if (threadIdx.x == 0) c[o] = bfv[o] + red[0] + red[1] + red[2] + red[3];
}

// LayerNorm over 256 dims; 4 rows/block; fp32 in, bf16 out
__global__ __launch_bounds__(256) void ln_kernel(const float* __restrict__ x,
                                                 const float* __restrict__ gw,
                                                 const float* __restrict__ gb,
                                                 ushort_t* __restrict__ out, long M) {
  long row = (long)blockIdx.x * 4 + (threadIdx.x >> 6);
  if (row >= M) return;
  int lane = threadIdx.x & 63;
  float4 v = *(const float4*)(x + row * 256 + lane * 4);
  float s = v.x + v.y + v.z + v.w;
  float s2 = v.x * v.x + v.y * v.y + v.z * v.z + v.w * v.w;
#pragma unroll
  for (int o = 32; o >= 1; o >>= 1) {
    s += __shfl_xor(s, o);
    s2 += __shfl_xor(s2, o);
  }
  float mu = s * (1.f / 256.f);
  float var = fmaxf(s2 * (1.f / 256.f) - mu * mu, 0.f);
  float rs = rsqrtf(var + 1e-5f);
  ushort4 o4;
  o4.x = f2bf((v.x - mu) * rs * gw[lane * 4 + 0] + gb[lane * 4 + 0]);
  o4.y = f2bf((v.y - mu) * rs * gw[lane * 4 + 1] + gb[lane * 4 + 1]);
  o4.z = f2bf((v.z - mu) * rs * gw[lane * 4 + 2] + gb[lane * 4 + 2]);
  o4.w = f2bf((v.w - mu) * rs * gw[lane * 4 + 3] + gb[lane * 4 + 3]);
  *(ushort4*)(out + row * 256 + lane * 4) = o4;
}

// row l2-normalize width-2048 bf16 matrix in place.
// QMODE: also A[row0+row] = (row . wg)/16.  else: also scale by G[b][d] (G chunk-based).
template <bool QMODE>
__global__ __launch_bounds__(256) void rownorm_kernel(ushort_t* __restrict__ mat,
                                                      const float* __restrict__ wg,
                                                      float* __restrict__ Av, long row0,
                                                      const float* __restrict__ G) {
  long lrow = blockIdx.x;
  int t = threadIdx.x;
  __shared__ float red[8];
  uint4 raw = *(const uint4*)(mat + lrow * 2048 + t * 8);
  ushort_t* u = (ushort_t*)&raw;
  float v[8];
  float ss = 0.f;
#pragma unroll
  for (int j = 0; j < 8; ++j) {
    v[j] = bf2f(u[j]);
    ss += v[j] * v[j];
  }
#pragma unroll
  for (int o = 32; o >= 1; o >>= 1) ss += __shfl_xor(ss, o);
  int w = t >> 6;
  if ((t & 63) == 0) red[w] = ss;
  __syncthreads();
  float rs = 1.f / fmaxf(sqrtf(red[0] + red[1] + red[2] + red[3]), 1e-12f);
  if constexpr (QMODE) {
    float av = 0.f;
#pragma unroll
    for (int j = 0; j < 8; ++j) {
      float qn = v[j] * rs;
      u[j] = f2bf(qn);
      av += qn * wg[t * 8 + j];
    }
    *(uint4*)(mat + lrow * 2048 + t * 8) = raw;
#pragma unroll
    for (int o = 32; o >= 1; o >>= 1) av += __shfl_xor(av, o);
    if ((t & 63) == 0) red[4 + w] = av;
    __syncthreads();
    if (t == 0) Av[row0 + lrow] = (red[4] + red[5] + red[6] + red[7]) * 0.0625f;
  } else {
    int b = (int)(lrow / kN);  // chunk-local batch
    const float* g = G + (long)b * 2048 + t * 8;
#pragma unroll
    for (int j = 0; j < 8; ++j) u[j] = f2bf(v[j] * rs * g[j]);
    *(uint4*)(mat + lrow * 2048 + t * 8) = raw;
  }
}

// invA[b0+blk] = 1/max(||A_b||, eps)
__global__ __launch_bounds__(256) void anorm_kernel(const float* __restrict__ Av,
                                                    float* __restrict__ invA, int b0) {
  int b = b0 + blockIdx.x;
  __shared__ float red[4];
  float s = 0.f;
  for (int n = threadIdx.x; n < kN; n += 256) {
    float a = Av[(long)b * kN + n];
    s += a * a;
  }
#pragma unroll
  for (int o = 32; o >= 1; o >>= 1) s += __shfl_xor(s, o);
  if ((threadIdx.x & 63) == 0) red[threadIdx.x >> 6] = s;
  __syncthreads();
  if (threadIdx.x == 0)
    invA[b] = 1.f / fmaxf(sqrtf(red[0] + red[1] + red[2] + red[3]), 1e-12f);
}

// Gpart[s][by][d0:d0+8] = sum_{n in slice s} Av[(b0+by)*kN+n] * qc[by*kN+n][d]
// grid: (1, NB, kGS), 256 threads; thread t owns d = t*8 .. t*8+7
__global__ __launch_bounds__(256) void gsplit_kernel(const float* __restrict__ Av,
                                                     const ushort_t* __restrict__ qc,
                                                     float* __restrict__ Gpart, int b0,
                                                     int NB) {
  const int by = blockIdx.y;
  const int s = blockIdx.z;
  const int d = threadIdx.x * 8;
  const int rowsPer = (kN + kGS - 1) / kGS;  // 25
  const long n0 = (long)s * rowsPer;
  const long n1 = (n0 + rowsPer < kN) ? n0 + rowsPer : kN;
  const float* ap = Av + (long)(b0 + by) * kN;
  const ushort_t* p = qc + ((long)by * kN + n0) * 2048 + d;
  float acc[8] = {0.f, 0.f, 0.f, 0.f, 0.f, 0.f, 0.f, 0.f};
  for (long n = n0; n < n1; ++n, p += 2048) {
    uint4 raw = *(const uint4*)p;
    const ushort_t* u = (const ushort_t*)&raw;
    const float a = ap[n];
#pragma unroll
    for (int j = 0; j < 8; ++j) acc[j] += a * bf2f(u[j]);
  }
  float* o = Gpart + ((long)s * NB + by) * 2048 + d;
#pragma unroll
  for (int j = 0; j < 8; ++j) o[j] = acc[j];
}

// G[(b0+by)][d] = invA[b0+by] * sum_s Gpart[s][by][d]
__global__ __launch_bounds__(256) void greduce_kernel(const float* __restrict__ Gpart,
                                                      const float* __restrict__ invA,
                                                      float* __restrict__ G, int b0,
                                                      int NB) {
  const long i = (long)blockIdx.x * 256 + threadIdx.x;  // over NB*2048
  const int by = (int)(i >> 11);
  const int d = (int)(i & 2047);
  if (by >= NB) return;
  float s = 0.f;
  for (int k = 0; k < kGS; ++k) s += Gpart[((long)k * NB + by) * 2048 + d];
  G[(long)(b0 + by) * 2048 + d] = s * invA[b0 + by];
}

// ---------------- GEMM: C = A @ W^T (+epilogue).  A: MxK bf16, W: NoutxK bf16 ----
// 128x128 tile, 4 waves (2x2 of 64x64), BK=32, mfma_f32_16x16x32_bf16.
// EPI 5: bf16 store (+bias if non-null)
// EPI 2: f32 store: v + auxf[idx]   (bias = cvec)
// EPI 6: f32 RMW:   out0[idx] += v
// EPI 3: bf16 gelu(v)
// EPI 4: f32 RMW:   out0[idx] += (row%kN==0 ? bf2f(auxb[idx]) : v)
template <int EPI, int LDO>
__global__ __launch_bounds__(256) void gemm_kernel(
    const ushort_t* __restrict__ A, const ushort_t* __restrict__ W, int M, int K,
    const float* __restrict__ bias, const float* __restrict__ auxf,
    const ushort_t* __restrict__ auxb, void* __restrict__ out0) {
  __shared__ ushort_t As[128 * 32];
  __shared__ ushort_t Ws[128 * 32];
  const int t = threadIdx.x;
  const int wave = t >> 6;
  const int lane = t & 63;
  const int n0 = blockIdx.x * 128;
  const int m0 = blockIdx.y * 128;
  const int wm = (wave >> 1) * 64;
  const int wn = (wave & 1) * 64;

  f32x4 acc[4][4];
#pragma unroll
  for (int i = 0; i < 4; ++i)
#pragma unroll
    for (int j = 0; j < 4; ++j) acc[i][j] = f32x4{0.f, 0.f, 0.f, 0.f};

  const int r4 = t >> 2;
  const int c8 = (t & 3) * 8;
  long ar0 = m0 + r4;      if (ar0 > M - 1) ar0 = M - 1;
  long ar1 = m0 + 64 + r4; if (ar1 > M - 1) ar1 = M - 1;
  const ushort_t* gA0 = A + ar0 * K + c8;
  const ushort_t* gA1 = A + ar1 * K + c8;
  const ushort_t* gW0 = W + (long)(n0 + r4) * K + c8;
  const ushort_t* gW1 = W + (long)(n0 + 64 + r4) * K + c8;
  char* la = (char*)As + wave * 1024;
  char* lw = (char*)Ws + wave * 1024;

  const int frow = lane & 15;
  const int kg = lane >> 4;

  for (int k0 = 0; k0 < K; k0 += 32) {
    gload16(gA0 + k0, la);
    gload16(gA1 + k0, la + 4096);
    gload16(gW0 + k0, lw);
    gload16(gW1 + k0, lw + 4096);
    __syncthreads();
    bf16x8 af[4], bw[4];
#pragma unroll
    for (int i = 0; i < 4; ++i)
      af[i] = *(const bf16x8*)&As[(wm + i * 16 + frow) * 32 + kg * 8];
#pragma unroll
    for (int i = 0; i < 4; ++i)
      bw[i] = *(const bf16x8*)&Ws[(wn + i * 16 + frow) * 32 + kg * 8];
#pragma unroll
    for (int mi = 0; mi < 4; ++mi)
#pragma unroll
      for (int ni = 0; ni < 4; ++ni)
        acc[mi][ni] =
            __builtin_amdgcn_mfma_f32_16x16x32_bf16(af[mi], bw[ni], acc[mi][ni], 0, 0, 0);
    __syncthreads();
  }

#pragma unroll
  for (int mi = 0; mi < 4; ++mi) {
#pragma unroll
    for (int ni = 0; ni < 4; ++ni) {
      const int gn = n0 + wn + ni * 16 + frow;
#pragma unroll
      for (int j = 0; j < 4; ++j) {
        const int gmi = m0 + wm + mi * 16 + kg * 4 + j;
        if (gmi >= M) continue;
        const long idx = (long)gmi * LDO + gn;
        float v = acc[mi][ni][j];
        if (bias) v += bias[gn];
        if constexpr (EPI == 5) {
          ((ushort_t*)out0)[idx] = f2bf(v);
        } else if constexpr (EPI == 2) {
          ((float*)out0)[idx] = v + auxf[idx];
        } else if constexpr (EPI == 6) {
          ((float*)out0)[idx] += v;
        } else if constexpr (EPI == 3) {
          ((ushort_t*)out0)[idx] = f2bf(0.5f * v * (1.0f + erff(v * 0.70710678118654752f)));
        } else {  // EPI == 4
          const bool cls = (gmi % kN) == 0;
          const float add = cls ? bf2f(auxb[idx]) : v;
          ((float*)out0)[idx] += add;
        }
      }
    }
  }
}

// ---------------- host ----------------

extern "C" void kernel_launch(void* const* d_in, const int* in_sizes, int n_in,
                              void* d_out, int out_size, void* d_ws, size_t ws_size,
                              hipStream_t stream) {
  const float* x = (const float*)d_in[0];
  const float* n1w = (const float*)d_in[1];
  const float* n1b = (const float*)d_in[2];
  const float* wq = (const float*)d_in[3];
  const float* bq = (const float*)d_in[4];
  const float* wk = (const float*)d_in[5];
  const float* bk = (const float*)d_in[6];
  const float* wg = (const float*)d_in[7];
  const float* wp = (const float*)d_in[8];
  const float* bp = (const float*)d_in[9];
  const float* wf = (const float*)d_in[10];
  const float* bfv = (const float*)d_in[11];
  const float* n2w = (const float*)d_in[12];
  const float* n2b = (const float*)d_in[13];
  const float* w1 = (const float*)d_in[14];
  const float* b1 = (const float*)d_in[15];
  const float* w2 = (const float*)d_in[16];
  const float* b2 = (const float*)d_in[17];
  float* out = (float*)d_out;  // also serves as the fp32 x2 accumulator

  // ---- workspace layout (adaptive chunking over batches) ----
  char* ws = (char*)d_ws;
  size_t off = 0;
  auto alloc = [&](size_t bytes) {
    size_t o = off;
    off += (bytes + 255) & ~(size_t)255;
    return o;
  };
  ushort_t* wq_bf = (ushort_t*)(ws + alloc((size_t)2048 * 256 * 2));
  ushort_t* wk_bf = (ushort_t*)(ws + alloc((size_t)2048 * 256 * 2));
  ushort_t* wpT_bf = (ushort_t*)(ws + alloc((size_t)2048 * 2048 * 2));
  ushort_t* wf_bf = (ushort_t*)(ws + alloc((size_t)256 * 2048 * 2));
  ushort_t* w1_bf = (ushort_t*)(ws + alloc((size_t)1024 * 256 * 2));
  ushort_t* w2_bf = (ushort_t*)(ws + alloc((size_t)256 * 1024 * 2));
  ushort_t* wfp_bf = (ushort_t*)(ws + alloc((size_t)256 * 2048 * 2));
  float* cvec = (float*)(ws + alloc(256 * 4));
  float* Av = (float*)(ws + alloc((size_t)kM * 4));
  float* invA = (float*)(ws + alloc(64));
  float* G = (float*)(ws + alloc((size_t)16 * 2048 * 4));
  float* Gpart = (float*)(ws + alloc((size_t)kGS * 16 * 2048 * 4));  // worst-case NB=16
  ushort_t* xn = (ushort_t*)(ws + alloc((size_t)kM * 256 * 2));
  size_t fixed = off;

  int CH = 0;
  for (int c : {1, 2, 4, 8, 16}) {
    size_t big = (size_t)(16 / c) * kN * 2048 * 2;
    if (fixed + big + 256 <= ws_size) { CH = c; break; }
  }
  if (CH == 0) return;  // cannot fit even minimal footprint
  const int NB = 16 / CH;
  ushort_t* big = (ushort_t*)(ws + alloc((size_t)NB * kN * 2048 * 2));

  auto mt = [](long m) { return (int)((m + 127) / 128); };

  // ---- weight prep ----
  cast_kernel<<<512, 256, 0, stream>>>(wq, wq_bf, 2048 * 256 / 4);
  cast_kernel<<<512, 256, 0, stream>>>(wk, wk_bf, 2048 * 256 / 4);
  cast_kernel<<<512, 256, 0, stream>>>(wf, wf_bf, 256 * 2048 / 4);
  cast_kernel<<<256, 256, 0, stream>>>(w1, w1_bf, 1024 * 256 / 4);
  cast_kernel<<<256, 256, 0, stream>>>(w2, w2_bf, 256 * 1024 / 4);
  transpose_cast_kernel<<<dim3(64, 64), 256, 0, stream>>>(wp, wpT_bf, 2048);
  cvec_kernel<<<256, 256, 0, stream>>>(wf, bp, bfv, cvec);
  // wfp = wf @ wp  (256 x 2048, bf16)
  gemm_kernel<5, 2048><<<dim3(16, 2), 256, 0, stream>>>(
      wf_bf, wpT_bf, 256, 2048, nullptr, nullptr, nullptr, wfp_bf);

  // ---- LN1 (full M) ----
  ln_kernel<<<(int)((kM + 3) / 4), 256, 0, stream>>>(x, n1w, n1b, xn, kM);

  // ---- attention path, chunked over whole batches ----
  for (int c = 0; c < CH; ++c) {
    const int b0 = c * NB;
    const long r0 = (long)b0 * kN;
    const long Mc = (long)NB * kN;
    const int mtc = mt(Mc);
    // q = xn@wq^T + bq
    gemm_kernel<5, 2048><<<dim3(16, mtc), 256, 0, stream>>>(
        xn + r0 * 256, wq_bf, (int)Mc, 256, bq, nullptr, nullptr, big);
    // normalize q rows, A
    rownorm_kernel<true><<<(int)Mc, 256, 0, stream>>>(big, wg, Av, r0, nullptr);
    // ||A|| per batch, then G via split reduction
    anorm_kernel<<<NB, 256, 0, stream>>>(Av, invA, b0);
    gsplit_kernel<<<dim3(1, NB, kGS), 256, 0, stream>>>(Av, big, Gpart, b0, NB);
    greduce_kernel<<<(NB * 2048 + 255) / 256, 256, 0, stream>>>(Gpart, invA, G, b0, NB);
    // out = x + q@wf^T + c
    gemm_kernel<2, 256><<<dim3(2, mtc), 256, 0, stream>>>(
        big, wf_bf, (int)Mc, 2048, cvec, x + r0 * 256, nullptr, out + r0 * 256);
    // k = xn@wk^T + bk
    gemm_kernel<5, 2048><<<dim3(16, mtc), 256, 0, stream>>>(
        xn + r0 * 256, wk_bf, (int)Mc, 256, bk, nullptr, nullptr, big);
    // normalize k rows and scale by G
    rownorm_kernel<false><<<(int)Mc, 256, 0, stream>>>(big, nullptr, nullptr, 0,
                                                       G + (long)b0 * 2048);
    // out += kk@wfp^T
    gemm_kernel<6, 256><<<dim3(2, mtc), 256, 0, stream>>>(
        big, wfp_bf, (int)Mc, 2048, nullptr, nullptr, nullptr, out + r0 * 256);
  }

  // ---- LN2 (full M): out(f32) -> xn ----
  ln_kernel<<<(int)((kM + 3) / 4), 256, 0, stream>>>(out, n2w, n2b, xn, kM);

  // ---- MLP, chunked ----
  for (int c = 0; c < CH; ++c) {
    const long r0 = (long)(c * NB) * kN;
    const long Mc = (long)NB * kN;
    const int mtc = mt(Mc);
    // hdn = gelu(xn2@w1^T + b1)
    gemm_kernel<3, 1024><<<dim3(8, mtc), 256, 0, stream>>>(
        xn + r0 * 256, w1_bf, (int)Mc, 256, b1, nullptr, nullptr, big);
    // out += (cls ? xn2 : hdn@w2^T + b2)
    gemm_kernel<4, 256><<<dim3(2, mtc), 256, 0, stream>>>(
        big, w2_bf, (int)Mc, 1024, b2, nullptr, xn + r0 * 256, out + r0 * 256);
  }
}